// Round 1
// baseline (819.365 us; speedup 1.0000x reference)
//
#include <hip/hip_runtime.h>

// ---------------------------------------------------------------------------
// Mapping_64725157151005 — bf16 MFMA pipeline.
// B=8, P=256, DM=1024, DL=4096, H=16, DK=64, V=8192.
// Round 2 fix: attention P-tile LDS write->read race (TBAA across
// ushort4/short8 views could drop the lgkmcnt wait). Now: matching signed
// types + explicit __syncthreads() between P-pack and PV.
// ---------------------------------------------------------------------------

typedef __attribute__((ext_vector_type(8)))  short          short8;
typedef __attribute__((ext_vector_type(4)))  short          short4v;
typedef __attribute__((ext_vector_type(4)))  float          f32x4;
typedef __attribute__((ext_vector_type(16))) float          f32x16;
typedef __attribute__((ext_vector_type(8)))  unsigned short ushort8;

__device__ __forceinline__ unsigned short f2bf(float f) {
    unsigned int u = __builtin_bit_cast(unsigned int, f);
    u += 0x7fffu + ((u >> 16) & 1u);          // RNE
    return (unsigned short)(u >> 16);
}

// async global->LDS, 16B per lane; LDS dst = wave-uniform base + lane*16
__device__ __forceinline__ void gld_lds16(const ushort* g, ushort* l) {
    __builtin_amdgcn_global_load_lds(
        (const __attribute__((address_space(1))) void*)g,
        (__attribute__((address_space(3))) void*)l, 16, 0, 0);
}

// ---------------------------------------------------------------------------
// f32 -> bf16 elementwise convert
// ---------------------------------------------------------------------------
__global__ __launch_bounds__(256) void conv_f32_bf16(
    const float* __restrict__ in, ushort* __restrict__ out, int n)
{
    int i = (blockIdx.x * 256 + threadIdx.x) * 8;
    if (i >= n) return;
    float4 a = *(const float4*)(in + i);
    float4 b = *(const float4*)(in + i + 4);
    ushort8 o = {f2bf(a.x), f2bf(a.y), f2bf(a.z), f2bf(a.w),
                 f2bf(b.x), f2bf(b.y), f2bf(b.z), f2bf(b.w)};
    *(ushort8*)(out + i) = o;
}

// ---------------------------------------------------------------------------
// f32 [R][C] -> bf16 [C][R] transpose-convert (R,C multiples of 32)
// ---------------------------------------------------------------------------
__global__ __launch_bounds__(256) void transconv(
    const float* __restrict__ in, ushort* __restrict__ out, int R, int C)
{
    __shared__ float t[32][33];
    const int tx = threadIdx.x & 31, ty = threadIdx.x >> 5;
    const int bx = blockIdx.x, by = blockIdx.y;   // C-tile, R-tile
#pragma unroll
    for (int i = 0; i < 4; ++i)
        t[ty + 8 * i][tx] = in[(size_t)(by * 32 + ty + 8 * i) * C + bx * 32 + tx];
    __syncthreads();
#pragma unroll
    for (int i = 0; i < 4; ++i)
        out[(size_t)(bx * 32 + ty + 8 * i) * R + by * 32 + tx] = f2bf(t[tx][ty + 8 * i]);
}

// ---------------------------------------------------------------------------
// C[M,N] = A[M,K] @ BT[N,K]^T + bias, both operands bf16 K-major.
// m97 structure: 128x128 tile, BK=32, 256 thr (4 waves 2x2), 16x16x32 MFMA,
// global_load_lds(16B), XOR-swizzled 16B chunks (2-way banks on ds_read_b128).
// M,N % 128 == 0, K % 32 == 0.
// ---------------------------------------------------------------------------
template<int OUT_BF16, int BIAS_ROW>
__global__ __launch_bounds__(256) void gemm_bt(
    const ushort* __restrict__ A, const ushort* __restrict__ BT,
    const float* __restrict__ bias, void* __restrict__ Cout,
    int M, int N, int K, float oscale)
{
    __shared__ ushort As[128 * 32];
    __shared__ ushort Bs[128 * 32];
    const int tid = threadIdx.x;
    const int w = tid >> 6, lane = tid & 63;
    const int m = lane & 15, quad = lane >> 4;
    const int wr = w >> 1, wc = w & 1;
    const int bx = blockIdx.x, by = blockIdx.y;

    f32x4 acc[4][4];
#pragma unroll
    for (int i = 0; i < 4; ++i)
#pragma unroll
        for (int j = 0; j < 4; ++j)
#pragma unroll
            for (int r = 0; r < 4; ++r) acc[i][j][r] = 0.f;

    // staging: wave w stages rows [w*32, w*32+32) of both tiles (2 issues each)
    const int r_i = lane >> 2;                                  // 0..15
    const int ccl = (lane & 3) ^ ((lane >> 2) & 3) ^ quad;      // swizzled logical chunk
    const ushort* Ag = A  + (size_t)(by * 128 + w * 32 + r_i) * K + ccl * 8;
    const ushort* Bg = BT + (size_t)(bx * 128 + w * 32 + r_i) * K + ccl * 8;
    ushort* AsW = As + w * 1024;
    ushort* BsW = Bs + w * 1024;
    const size_t rowstep = (size_t)16 * K;

    // compute-read offsets: phys chunk = quad ^ swz4(row), swz4 = (m&3)^(m>>2)
    const int phys = (quad ^ (m & 3) ^ (m >> 2)) * 8;
    int aoff[4], boff[4];
#pragma unroll
    for (int i = 0; i < 4; ++i) {
        aoff[i] = (wr * 64 + i * 16 + m) * 32 + phys;
        boff[i] = (wc * 64 + i * 16 + m) * 32 + phys;
    }

    const int kIters = K >> 5;
    for (int kt = 0; kt < kIters; ++kt) {
        __syncthreads();
        gld_lds16(Ag, AsW);
        gld_lds16(Ag + rowstep, AsW + 512);
        gld_lds16(Bg, BsW);
        gld_lds16(Bg + rowstep, BsW + 512);
        Ag += 32; Bg += 32;
        __syncthreads();
        short8 af[4], bf[4];
#pragma unroll
        for (int i = 0; i < 4; ++i) af[i] = *(const short8*)(As + aoff[i]);
#pragma unroll
        for (int i = 0; i < 4; ++i) bf[i] = *(const short8*)(Bs + boff[i]);
#pragma unroll
        for (int i = 0; i < 4; ++i)
#pragma unroll
            for (int j = 0; j < 4; ++j)
                acc[i][j] = __builtin_amdgcn_mfma_f32_16x16x32_bf16(
                    af[i], bf[j], acc[i][j], 0, 0, 0);
    }

    // epilogue: C row = mi*16 + quad*4 + r, col = ni*16 + m
    const int row0 = by * 128 + wr * 64;
    const int col0 = bx * 128 + wc * 64;
#pragma unroll
    for (int i = 0; i < 4; ++i) {
#pragma unroll
        for (int j = 0; j < 4; ++j) {
            const int c = col0 + j * 16 + m;
            float bcol = BIAS_ROW ? 0.f : bias[c];
#pragma unroll
            for (int r = 0; r < 4; ++r) {
                const int rw = row0 + i * 16 + quad * 4 + r;
                float v = acc[i][j][r] + (BIAS_ROW ? bias[rw] : bcol);
                v *= oscale;
                if (OUT_BF16)
                    ((ushort*)Cout)[(size_t)rw * N + c] = f2bf(v);
                else
                    ((float*)Cout)[(size_t)rw * N + c] = v;
            }
        }
    }
}

// ---------------------------------------------------------------------------
// MFMA flash attention. qb [2048,1024] bf16 (PRE-SCALED by log2e/64),
// kb [8192,1024] bf16, vT [1024,8192] bf16 (v-proj transposed), out bf16.
// Block = 128 thr (2 waves), block p-tile 64 (32 p per wave), v-tile 128.
// S^T = K * Q^T via 32x32x16 MFMA; P = exp2(S^T) (no max-sub: |scores| small);
// P -> padded LDS -> A-operand of PV. grid = 8b * 16h * 4pt = 512 blocks.
// ---------------------------------------------------------------------------
__global__ __launch_bounds__(128) void attn_mfma(
    const ushort* __restrict__ qb, const ushort* __restrict__ kb,
    const ushort* __restrict__ vT, ushort* __restrict__ mappedb)
{
    __shared__ ushort Qs[64 * 64];     //  8 KB  [p][k]
    __shared__ ushort Ks[128 * 64];    // 16 KB  [v][k]  (16B-chunk swizzled)
    __shared__ ushort Vs[64 * 128];    // 16 KB  [d][v]  (16B-chunk swizzled)
    __shared__ short  Ps[64 * 136];    // 17 KB  [p][v]  (+8 pad), signed!

    const int tid = threadIdx.x;
    const int w = tid >> 6, lane = tid & 63;
    const int l31 = lane & 31, l5 = lane >> 5, quad = lane >> 4;
    const int idx = blockIdx.x;
    const int pt = idx & 3, h = (idx >> 2) & 15, b = idx >> 6;
    const int pbase = b * 256 + pt * 64;

    const int c8 = lane & 7, r8 = lane >> 3, c16 = lane & 15;

    // ---- stage Q once (8 issues of 1KB) ----
#pragma unroll
    for (int j = 0; j < 4; ++j) {
        const int t = w * 4 + j;
        const ushort* g = qb + (size_t)(pbase + t * 8 + r8) * 1024 + h * 64 + c8 * 8;
        gld_lds16(g, Qs + t * 512);
    }
    __syncthreads();
    short8 qf[4];
#pragma unroll
    for (int ks = 0; ks < 4; ++ks)
        qf[ks] = *(const short8*)(Qs + (w * 32 + l31) * 64 + ks * 16 + l5 * 8);

    f32x16 o[2];
#pragma unroll
    for (int dt = 0; dt < 2; ++dt)
#pragma unroll
        for (int r = 0; r < 16; ++r) o[dt][r] = 0.f;
    float lpart = 0.f;

    const int ccK = c8 ^ r8;           // Ks staging logical chunk (swizzle)
    const int prow = (w * 32 + l31) * 136;

    for (int vt = 0; vt < 8192; vt += 128) {
        __syncthreads();
        // ---- stage K (16KB) + V^T (16KB), 8 issues each per wave ----
#pragma unroll
        for (int i = 0; i < 8; ++i) {
            const int t = w * 8 + i;
            const ushort* gk = kb + (size_t)(vt + t * 8 + r8) * 1024 + h * 64 + ccK * 8;
            gld_lds16(gk, Ks + t * 512);
            const int d_l = t * 4 + quad;
            const int ccV = c16 ^ (d_l & 15);
            const ushort* gv = vT + (size_t)(h * 64 + d_l) * 8192 + vt + ccV * 8;
            gld_lds16(gv, Vs + t * 512);
        }
        __syncthreads();

        // ---- S^T = K * Q^T  (4 v-subtiles of 32, K=64 over 4 ksteps) ----
        f32x16 st[4];
#pragma unroll
        for (int v4 = 0; v4 < 4; ++v4)
#pragma unroll
            for (int r = 0; r < 16; ++r) st[v4][r] = 0.f;
#pragma unroll
        for (int v4 = 0; v4 < 4; ++v4) {
            const int row = (v4 * 32 + l31) * 64;
            const int sw = l31 & 7;
#pragma unroll
            for (int ks = 0; ks < 4; ++ks) {
                const int ph = ((ks * 2 + l5) ^ sw) * 8;
                short8 kf = *(const short8*)(Ks + row + ph);
                st[v4] = __builtin_amdgcn_mfma_f32_32x32x16_bf16(kf, qf[ks], st[v4], 0, 0, 0);
            }
        }

        // ---- P = exp2(S^T); accumulate l; pack to Ps[p][v] ----
#pragma unroll
        for (int v4 = 0; v4 < 4; ++v4) {
#pragma unroll
            for (int g = 0; g < 4; ++g) {
                float e0 = exp2f(st[v4][g * 4 + 0]);
                float e1 = exp2f(st[v4][g * 4 + 1]);
                float e2 = exp2f(st[v4][g * 4 + 2]);
                float e3 = exp2f(st[v4][g * 4 + 3]);
                lpart += (e0 + e1) + (e2 + e3);
                short4v pk = {(short)f2bf(e0), (short)f2bf(e1),
                              (short)f2bf(e2), (short)f2bf(e3)};
                *(short4v*)(Ps + prow + v4 * 32 + g * 8 + l5 * 4) = pk;
            }
        }
        __syncthreads();   // Ps writes drained & fenced before PV reads

        // ---- O += P * V  (8 ksteps of 16 over v, 2 d-tiles of 32) ----
#pragma unroll
        for (int k8 = 0; k8 < 8; ++k8) {
            short8 pf = *(const short8*)(Ps + prow + k8 * 16 + l5 * 8);
#pragma unroll
            for (int dt = 0; dt < 2; ++dt) {
                const int d_l = dt * 32 + l31;
                const int ph = ((k8 * 2 + l5) ^ (d_l & 15)) * 8;
                short8 vf = *(const short8*)(Vs + d_l * 128 + ph);
                o[dt] = __builtin_amdgcn_mfma_f32_32x32x16_bf16(pf, vf, o[dt], 0, 0, 0);
            }
        }
    }

    // ---- epilogue: normalize by l, write bf16 ----
    float lfull = lpart + __shfl_xor(lpart, 32, 64);
    float rinv = 1.0f / lfull;
#pragma unroll
    for (int r = 0; r < 16; ++r) {
        const int poff = (r & 3) + 8 * (r >> 2) + 4 * l5;
        const float sc = __shfl(rinv, poff, 64);
        const size_t grow = (size_t)(pbase + w * 32 + poff) * 1024;
#pragma unroll
        for (int dt = 0; dt < 2; ++dt)
            mappedb[grow + h * 64 + dt * 32 + l31] = f2bf(o[dt][r] * sc);
    }
}

// ---------------------------------------------------------------------------
extern "C" void kernel_launch(void* const* d_in, const int* in_sizes, int n_in,
                              void* d_out, int out_size, void* d_ws, size_t ws_size,
                              hipStream_t stream)
{
    const float* query = (const float*)d_in[0];
    const float* key   = (const float*)d_in[1];
    const float* value = (const float*)d_in[2];
    const float* Wq    = (const float*)d_in[3];
    const float* bq    = (const float*)d_in[4];
    const float* Wk    = (const float*)d_in[5];
    const float* bk    = (const float*)d_in[6];
    const float* Wv    = (const float*)d_in[7];
    const float* bv    = (const float*)d_in[8];
    const float* Wo    = (const float*)d_in[9];
    const float* bo    = (const float*)d_in[10];
    float* out = (float*)d_out;

    // ws layout (<= 80 MB): tmpb 64MB | wslot 8MB | queryb 4MB | qb 4MB
    // mappedb aliases tmpb[0:4MB) (tmp dead after vproj).
    // d_out (32MB) used as scratch for kb/vT, fully overwritten by final gemm.
    char* ws = (char*)d_ws;
    ushort* tmpb    = (ushort*)ws;
    ushort* wslot   = (ushort*)(ws + (64ull << 20));
    ushort* queryb  = (ushort*)(ws + (72ull << 20));
    ushort* qb      = (ushort*)(ws + (76ull << 20));
    ushort* mappedb = (ushort*)ws;
    ushort* kb      = (ushort*)d_out;
    ushort* vT      = (ushort*)((char*)d_out + (16ull << 20));

    const float QSCALE = 1.4426950408889634f / 64.0f;   // log2(e)/64 folded into q

    // k-projection: kb[8192,1024] = key @ Wk + bk
    conv_f32_bf16<<<16384, 256, 0, stream>>>(key, tmpb, 8192 * 4096);
    transconv<<<dim3(32, 128), 256, 0, stream>>>(Wk, wslot, 4096, 1024);
    gemm_bt<1, 0><<<dim3(8, 64), 256, 0, stream>>>(tmpb, wslot, bk, kb,
                                                   8192, 1024, 4096, 1.0f);
    // v-projection, TRANSPOSED: vT[1024,8192] = WvT @ value^T  (row bias bv)
    conv_f32_bf16<<<16384, 256, 0, stream>>>(value, tmpb, 8192 * 4096);
    transconv<<<dim3(32, 128), 256, 0, stream>>>(Wv, wslot, 4096, 1024);
    gemm_bt<1, 1><<<dim3(64, 8), 256, 0, stream>>>(wslot, tmpb, bv, vT,
                                                   1024, 8192, 4096, 1.0f);
    // q-projection (pre-scaled): qb[2048,1024] = (query @ Wq + bq) * QSCALE
    conv_f32_bf16<<<1024, 256, 0, stream>>>(query, queryb, 2048 * 1024);
    transconv<<<dim3(32, 32), 256, 0, stream>>>(Wq, wslot, 1024, 1024);
    gemm_bt<1, 0><<<dim3(8, 16), 256, 0, stream>>>(queryb, wslot, bq, qb,
                                                   2048, 1024, 1024, QSCALE);
    // attention -> mappedb [2048,1024] bf16
    attn_mfma<<<512, 128, 0, stream>>>(qb, kb, vT, mappedb);
    // output projection (fp32 out): out[2048,4096] = mapped @ Wo + bo
    transconv<<<dim3(128, 32), 256, 0, stream>>>(Wo, wslot, 1024, 4096);
    gemm_bt<0, 0><<<dim3(32, 16), 256, 0, stream>>>(mappedb, wslot, bo, out,
                                                    2048, 4096, 1024, 1.0f);
}

// Round 3
// 722.745 us; speedup vs baseline: 1.1337x; 1.1337x over previous
//
#include <hip/hip_runtime.h>

// ---------------------------------------------------------------------------
// Mapping_64725157151005 — bf16 MFMA pipeline.
// B=8, P=256, DM=1024, DL=4096, H=16, DK=64, V=8192.
// Round 1 (this session): attn restructured to 4-wave blocks (p-half x v-half
// per wave). Ps is now wave-private (each wave PV-reads only the v-half it
// packed) -> pack->PV block barrier removed (wave-local lgkmcnt fence),
// cvt_pk_bf16_f32 pack, setprio around MFMA clusters, linear cross-wave
// o/l reduce in epilogue (exact: no max-sub softmax).
// ---------------------------------------------------------------------------

typedef __attribute__((ext_vector_type(8)))  short          short8;
typedef __attribute__((ext_vector_type(4)))  float          f32x4;
typedef __attribute__((ext_vector_type(16))) float          f32x16;
typedef __attribute__((ext_vector_type(8)))  unsigned short ushort8;
typedef __attribute__((ext_vector_type(2)))  unsigned int   uint2v;

__device__ __forceinline__ unsigned short f2bf(float f) {
    unsigned int u = __builtin_bit_cast(unsigned int, f);
    u += 0x7fffu + ((u >> 16) & 1u);          // RNE
    return (unsigned short)(u >> 16);
}

// async global->LDS, 16B per lane; LDS dst = wave-uniform base + lane*16
__device__ __forceinline__ void gld_lds16(const ushort* g, ushort* l) {
    __builtin_amdgcn_global_load_lds(
        (const __attribute__((address_space(1))) void*)g,
        (__attribute__((address_space(3))) void*)l, 16, 0, 0);
}

// ---------------------------------------------------------------------------
// f32 -> bf16 elementwise convert
// ---------------------------------------------------------------------------
__global__ __launch_bounds__(256) void conv_f32_bf16(
    const float* __restrict__ in, ushort* __restrict__ out, int n)
{
    int i = (blockIdx.x * 256 + threadIdx.x) * 8;
    if (i >= n) return;
    float4 a = *(const float4*)(in + i);
    float4 b = *(const float4*)(in + i + 4);
    ushort8 o = {f2bf(a.x), f2bf(a.y), f2bf(a.z), f2bf(a.w),
                 f2bf(b.x), f2bf(b.y), f2bf(b.z), f2bf(b.w)};
    *(ushort8*)(out + i) = o;
}

// ---------------------------------------------------------------------------
// f32 [R][C] -> bf16 [C][R] transpose-convert (R,C multiples of 32)
// ---------------------------------------------------------------------------
__global__ __launch_bounds__(256) void transconv(
    const float* __restrict__ in, ushort* __restrict__ out, int R, int C)
{
    __shared__ float t[32][33];
    const int tx = threadIdx.x & 31, ty = threadIdx.x >> 5;
    const int bx = blockIdx.x, by = blockIdx.y;   // C-tile, R-tile
#pragma unroll
    for (int i = 0; i < 4; ++i)
        t[ty + 8 * i][tx] = in[(size_t)(by * 32 + ty + 8 * i) * C + bx * 32 + tx];
    __syncthreads();
#pragma unroll
    for (int i = 0; i < 4; ++i)
        out[(size_t)(bx * 32 + ty + 8 * i) * R + by * 32 + tx] = f2bf(t[tx][ty + 8 * i]);
}

// ---------------------------------------------------------------------------
// C[M,N] = A[M,K] @ BT[N,K]^T + bias, both operands bf16 K-major.
// m97 structure: 128x128 tile, BK=32, 256 thr (4 waves 2x2), 16x16x32 MFMA,
// global_load_lds(16B), XOR-swizzled 16B chunks (2-way banks on ds_read_b128).
// M,N % 128 == 0, K % 32 == 0.
// ---------------------------------------------------------------------------
template<int OUT_BF16, int BIAS_ROW>
__global__ __launch_bounds__(256) void gemm_bt(
    const ushort* __restrict__ A, const ushort* __restrict__ BT,
    const float* __restrict__ bias, void* __restrict__ Cout,
    int M, int N, int K, float oscale)
{
    __shared__ ushort As[128 * 32];
    __shared__ ushort Bs[128 * 32];
    const int tid = threadIdx.x;
    const int w = tid >> 6, lane = tid & 63;
    const int m = lane & 15, quad = lane >> 4;
    const int wr = w >> 1, wc = w & 1;
    const int bx = blockIdx.x, by = blockIdx.y;

    f32x4 acc[4][4];
#pragma unroll
    for (int i = 0; i < 4; ++i)
#pragma unroll
        for (int j = 0; j < 4; ++j)
#pragma unroll
            for (int r = 0; r < 4; ++r) acc[i][j][r] = 0.f;

    // staging: wave w stages rows [w*32, w*32+32) of both tiles (2 issues each)
    const int r_i = lane >> 2;                                  // 0..15
    const int ccl = (lane & 3) ^ ((lane >> 2) & 3) ^ quad;      // swizzled logical chunk
    const ushort* Ag = A  + (size_t)(by * 128 + w * 32 + r_i) * K + ccl * 8;
    const ushort* Bg = BT + (size_t)(bx * 128 + w * 32 + r_i) * K + ccl * 8;
    ushort* AsW = As + w * 1024;
    ushort* BsW = Bs + w * 1024;
    const size_t rowstep = (size_t)16 * K;

    // compute-read offsets: phys chunk = quad ^ swz4(row), swz4 = (m&3)^(m>>2)
    const int phys = (quad ^ (m & 3) ^ (m >> 2)) * 8;
    int aoff[4], boff[4];
#pragma unroll
    for (int i = 0; i < 4; ++i) {
        aoff[i] = (wr * 64 + i * 16 + m) * 32 + phys;
        boff[i] = (wc * 64 + i * 16 + m) * 32 + phys;
    }

    const int kIters = K >> 5;
    for (int kt = 0; kt < kIters; ++kt) {
        __syncthreads();
        gld_lds16(Ag, AsW);
        gld_lds16(Ag + rowstep, AsW + 512);
        gld_lds16(Bg, BsW);
        gld_lds16(Bg + rowstep, BsW + 512);
        Ag += 32; Bg += 32;
        __syncthreads();
        short8 af[4], bf[4];
#pragma unroll
        for (int i = 0; i < 4; ++i) af[i] = *(const short8*)(As + aoff[i]);
#pragma unroll
        for (int i = 0; i < 4; ++i) bf[i] = *(const short8*)(Bs + boff[i]);
#pragma unroll
        for (int i = 0; i < 4; ++i)
#pragma unroll
            for (int j = 0; j < 4; ++j)
                acc[i][j] = __builtin_amdgcn_mfma_f32_16x16x32_bf16(
                    af[i], bf[j], acc[i][j], 0, 0, 0);
    }

    // epilogue: C row = mi*16 + quad*4 + r, col = ni*16 + m
    const int row0 = by * 128 + wr * 64;
    const int col0 = bx * 128 + wc * 64;
#pragma unroll
    for (int i = 0; i < 4; ++i) {
#pragma unroll
        for (int j = 0; j < 4; ++j) {
            const int c = col0 + j * 16 + m;
            float bcol = BIAS_ROW ? 0.f : bias[c];
#pragma unroll
            for (int r = 0; r < 4; ++r) {
                const int rw = row0 + i * 16 + quad * 4 + r;
                float v = acc[i][j][r] + (BIAS_ROW ? bias[rw] : bcol);
                v *= oscale;
                if (OUT_BF16)
                    ((ushort*)Cout)[(size_t)rw * N + c] = f2bf(v);
                else
                    ((float*)Cout)[(size_t)rw * N + c] = v;
            }
        }
    }
}

// ---------------------------------------------------------------------------
// MFMA flash attention, 4-wave blocks. qb [2048,1024] bf16 (PRE-SCALED by
// log2e/64), kb [8192,1024] bf16, vT [1024,8192] bf16, out bf16.
// Block = 256 thr (4 waves): wave (wp,wv) = (w>>1, w&1) handles p-rows
// [wp*32,wp*32+32) x v-columns [wv*64,wv*64+64) of each 128-v tile.
// Ps is wave-private (each wave PV-reads exactly its own packed v-half) ->
// no block barrier between pack and PV; wave-local lgkmcnt fence instead.
// o/l partials over v-halves combine LINEARLY in epilogue (no max-sub).
// grid = 8b * 16h * 4pt = 512 blocks -> 2 blocks/CU, 8 waves/CU (2/SIMD).
// ---------------------------------------------------------------------------
__global__ __launch_bounds__(256, 2) void attn_mfma(
    const ushort* __restrict__ qb, const ushort* __restrict__ kb,
    const ushort* __restrict__ vT, ushort* __restrict__ mappedb)
{
    __shared__ ushort Qs[64 * 64];     //  8 KB  [p][k]
    __shared__ ushort Ks[128 * 64];    // 16 KB  [v][k]  (16B-chunk swizzled)
    __shared__ ushort Vs[64 * 128];    // 16 KB  [d][v]  (16B-chunk swizzled)
    __shared__ short  Ps[64 * 136];    // 17 KB  [p][v]  (+8 pad), signed!

    const int tid = threadIdx.x;
    const int w = tid >> 6, lane = tid & 63;
    const int l31 = lane & 31, l5 = lane >> 5, quad = lane >> 4;
    const int wp = w >> 1, wv = w & 1;
    const int idx = blockIdx.x;
    const int pt = idx & 3, h = (idx >> 2) & 15, b = idx >> 6;
    const int pbase = b * 256 + pt * 64;

    const int c8 = lane & 7, r8 = lane >> 3, c16 = lane & 15;

    // ---- stage Q once (8 issues of 1KB across 4 waves) ----
#pragma unroll
    for (int j = 0; j < 2; ++j) {
        const int t = w * 2 + j;
        const ushort* g = qb + (size_t)(pbase + t * 8 + r8) * 1024 + h * 64 + c8 * 8;
        gld_lds16(g, Qs + t * 512);
    }
    __syncthreads();
    short8 qf[4];
#pragma unroll
    for (int ks = 0; ks < 4; ++ks)
        qf[ks] = *(const short8*)(Qs + (wp * 32 + l31) * 64 + ks * 16 + l5 * 8);

    f32x16 o[2];
#pragma unroll
    for (int dt = 0; dt < 2; ++dt)
#pragma unroll
        for (int r = 0; r < 16; ++r) o[dt][r] = 0.f;
    float lpart = 0.f;

    const int ccK = c8 ^ r8;           // Ks staging logical chunk (swizzle)
    const int prow = (wp * 32 + l31) * 136;

    for (int vt = 0; vt < 8192; vt += 128) {
        __syncthreads();
        // ---- stage K (16KB) + V^T (16KB), 4 issues each per wave ----
#pragma unroll
        for (int i = 0; i < 4; ++i) {
            const int t = w * 4 + i;
            const ushort* gk = kb + (size_t)(vt + t * 8 + r8) * 1024 + h * 64 + ccK * 8;
            gld_lds16(gk, Ks + t * 512);
            const int d_l = t * 4 + quad;
            const int ccV = c16 ^ (d_l & 15);
            const ushort* gv = vT + (size_t)(h * 64 + d_l) * 8192 + vt + ccV * 8;
            gld_lds16(gv, Vs + t * 512);
        }
        __syncthreads();

        // ---- S^T = K * Q^T  (2 v-subtiles of 32 for this wave's v-half) ----
        f32x16 st[2];
#pragma unroll
        for (int s = 0; s < 2; ++s)
#pragma unroll
            for (int r = 0; r < 16; ++r) st[s][r] = 0.f;
        __builtin_amdgcn_s_setprio(1);
#pragma unroll
        for (int s = 0; s < 2; ++s) {
            const int v4 = wv * 2 + s;
            const int row = (v4 * 32 + l31) * 64;
            const int sw = l31 & 7;
#pragma unroll
            for (int ks = 0; ks < 4; ++ks) {
                const int ph = ((ks * 2 + l5) ^ sw) * 8;
                short8 kf = *(const short8*)(Ks + row + ph);
                st[s] = __builtin_amdgcn_mfma_f32_32x32x16_bf16(kf, qf[ks], st[s], 0, 0, 0);
            }
        }
        __builtin_amdgcn_s_setprio(0);

        // ---- P = exp2(S^T); accumulate l; pack (cvt_pk) to private Ps rows ----
#pragma unroll
        for (int s = 0; s < 2; ++s) {
            const int v4 = wv * 2 + s;
#pragma unroll
            for (int g = 0; g < 4; ++g) {
                float e0 = exp2f(st[s][g * 4 + 0]);
                float e1 = exp2f(st[s][g * 4 + 1]);
                float e2 = exp2f(st[s][g * 4 + 2]);
                float e3 = exp2f(st[s][g * 4 + 3]);
                lpart += (e0 + e1) + (e2 + e3);
                unsigned int plo, phi;
                asm("v_cvt_pk_bf16_f32 %0, %1, %2" : "=v"(plo) : "v"(e0), "v"(e1));
                asm("v_cvt_pk_bf16_f32 %0, %1, %2" : "=v"(phi) : "v"(e2), "v"(e3));
                uint2v pk = {plo, phi};
                *(uint2v*)(Ps + prow + v4 * 32 + g * 8 + l5 * 4) = pk;
            }
        }
        // wave-local fence: Ps writes landed before this wave's PV reads.
        asm volatile("s_waitcnt lgkmcnt(0)" ::: "memory");
        __builtin_amdgcn_sched_barrier(0);

        // ---- O += P * V  (this wave's 4 ksteps of 16 v, 2 d-tiles of 32) ----
        __builtin_amdgcn_s_setprio(1);
#pragma unroll
        for (int k4 = 0; k4 < 4; ++k4) {
            const int k8 = wv * 4 + k4;
            short8 pf = *(const short8*)(Ps + prow + k8 * 16 + l5 * 8);
#pragma unroll
            for (int dt = 0; dt < 2; ++dt) {
                const int d_l = dt * 32 + l31;
                const int ph = ((k8 * 2 + l5) ^ (d_l & 15)) * 8;
                short8 vf = *(const short8*)(Vs + d_l * 128 + ph);
                o[dt] = __builtin_amdgcn_mfma_f32_32x32x16_bf16(pf, vf, o[dt], 0, 0, 0);
            }
        }
        __builtin_amdgcn_s_setprio(0);
    }

    // ---- cross-wave (v-half) linear reduce of o and l via LDS ----
    __syncthreads();                       // all Ks/Vs reads done; safe to reuse
    float* Red  = (float*)Ks;              // 2 * 64 * 32 f32 = 16 KB
    float* Lred = (float*)Vs;              // 128 f32
    if (wv == 1) {
#pragma unroll
        for (int dt = 0; dt < 2; ++dt)
#pragma unroll
            for (int r = 0; r < 16; ++r)
                Red[wp * 2048 + (dt * 16 + r) * 64 + lane] = o[dt][r];
        Lred[wp * 64 + lane] = lpart;
    }
    __syncthreads();
    if (wv == 0) {
#pragma unroll
        for (int dt = 0; dt < 2; ++dt)
#pragma unroll
            for (int r = 0; r < 16; ++r)
                o[dt][r] += Red[wp * 2048 + (dt * 16 + r) * 64 + lane];
        lpart += Lred[wp * 64 + lane];

        // ---- epilogue: normalize by l, write bf16 ----
        float lfull = lpart + __shfl_xor(lpart, 32, 64);
        float rinv = 1.0f / lfull;
#pragma unroll
        for (int r = 0; r < 16; ++r) {
            const int poff = (r & 3) + 8 * (r >> 2) + 4 * l5;
            const float sc = __shfl(rinv, poff, 64);
            const size_t grow = (size_t)(pbase + wp * 32 + poff) * 1024;
#pragma unroll
            for (int dt = 0; dt < 2; ++dt)
                mappedb[grow + h * 64 + dt * 32 + l31] = f2bf(o[dt][r] * sc);
        }
    }
}

// ---------------------------------------------------------------------------
extern "C" void kernel_launch(void* const* d_in, const int* in_sizes, int n_in,
                              void* d_out, int out_size, void* d_ws, size_t ws_size,
                              hipStream_t stream)
{
    const float* query = (const float*)d_in[0];
    const float* key   = (const float*)d_in[1];
    const float* value = (const float*)d_in[2];
    const float* Wq    = (const float*)d_in[3];
    const float* bq    = (const float*)d_in[4];
    const float* Wk    = (const float*)d_in[5];
    const float* bk    = (const float*)d_in[6];
    const float* Wv    = (const float*)d_in[7];
    const float* bv    = (const float*)d_in[8];
    const float* Wo    = (const float*)d_in[9];
    const float* bo    = (const float*)d_in[10];
    float* out = (float*)d_out;

    // ws layout (<= 80 MB): tmpb 64MB | wslot 8MB | queryb 4MB | qb 4MB
    // mappedb aliases tmpb[0:4MB) (tmp dead after vproj).
    // d_out (32MB) used as scratch for kb/vT, fully overwritten by final gemm.
    char* ws = (char*)d_ws;
    ushort* tmpb    = (ushort*)ws;
    ushort* wslot   = (ushort*)(ws + (64ull << 20));
    ushort* queryb  = (ushort*)(ws + (72ull << 20));
    ushort* qb      = (ushort*)(ws + (76ull << 20));
    ushort* mappedb = (ushort*)ws;
    ushort* kb      = (ushort*)d_out;
    ushort* vT      = (ushort*)((char*)d_out + (16ull << 20));

    const float QSCALE = 1.4426950408889634f / 64.0f;   // log2(e)/64 folded into q

    // k-projection: kb[8192,1024] = key @ Wk + bk
    conv_f32_bf16<<<16384, 256, 0, stream>>>(key, tmpb, 8192 * 4096);
    transconv<<<dim3(32, 128), 256, 0, stream>>>(Wk, wslot, 4096, 1024);
    gemm_bt<1, 0><<<dim3(8, 64), 256, 0, stream>>>(tmpb, wslot, bk, kb,
                                                   8192, 1024, 4096, 1.0f);
    // v-projection, TRANSPOSED: vT[1024,8192] = WvT @ value^T  (row bias bv)
    conv_f32_bf16<<<16384, 256, 0, stream>>>(value, tmpb, 8192 * 4096);
    transconv<<<dim3(32, 128), 256, 0, stream>>>(Wv, wslot, 4096, 1024);
    gemm_bt<1, 1><<<dim3(64, 8), 256, 0, stream>>>(wslot, tmpb, bv, vT,
                                                   1024, 8192, 4096, 1.0f);
    // q-projection (pre-scaled): qb[2048,1024] = (query @ Wq + bq) * QSCALE
    conv_f32_bf16<<<1024, 256, 0, stream>>>(query, queryb, 2048 * 1024);
    transconv<<<dim3(32, 32), 256, 0, stream>>>(Wq, wslot, 1024, 1024);
    gemm_bt<1, 0><<<dim3(8, 16), 256, 0, stream>>>(queryb, wslot, bq, qb,
                                                   2048, 1024, 1024, QSCALE);
    // attention -> mappedb [2048,1024] bf16  (4-wave blocks now)
    attn_mfma<<<512, 256, 0, stream>>>(qb, kb, vT, mappedb);
    // output projection (fp32 out): out[2048,4096] = mapped @ Wo + bo
    transconv<<<dim3(128, 32), 256, 0, stream>>>(Wo, wslot, 1024, 4096);
    gemm_bt<0, 0><<<dim3(32, 16), 256, 0, stream>>>(mappedb, wslot, bo, out,
                                                    2048, 4096, 1024, 1.0f);
}

// Round 4
// 713.015 us; speedup vs baseline: 1.1492x; 1.0136x over previous
//
#include <hip/hip_runtime.h>

// ---------------------------------------------------------------------------
// Mapping_64725157151005 — bf16 MFMA pipeline.
// B=8, P=256, DM=1024, DL=4096, H=16, DK=64, V=8192.
// Round 3: attn v2 — 512-thr blocks (8 waves: 2 wp x 4 wv), wave = 32p x 32v
// quarter of each 128-v tile; P held IN REGISTERS (cvt_pk_bf16_f32 +
// v_permlane32_swap_b32 rebuild the PV A-fragment from the S^T output
// layout) -> Ps LDS buffer deleted (58KB -> 40KB), no pack fence; 4-way
// cross-wave linear o/l reduce in epilogue. 16 waves/CU (4/SIMD).
// ---------------------------------------------------------------------------

typedef __attribute__((ext_vector_type(8)))  short          short8;
typedef __attribute__((ext_vector_type(4)))  float          f32x4;
typedef __attribute__((ext_vector_type(16))) float          f32x16;
typedef __attribute__((ext_vector_type(8)))  unsigned short ushort8;
typedef __attribute__((ext_vector_type(4)))  unsigned int   uint4v;

__device__ __forceinline__ unsigned short f2bf(float f) {
    unsigned int u = __builtin_bit_cast(unsigned int, f);
    u += 0x7fffu + ((u >> 16) & 1u);          // RNE
    return (unsigned short)(u >> 16);
}

// async global->LDS, 16B per lane; LDS dst = wave-uniform base + lane*16
__device__ __forceinline__ void gld_lds16(const ushort* g, ushort* l) {
    __builtin_amdgcn_global_load_lds(
        (const __attribute__((address_space(1))) void*)g,
        (__attribute__((address_space(3))) void*)l, 16, 0, 0);
}

// ---------------------------------------------------------------------------
// f32 -> bf16 elementwise convert
// ---------------------------------------------------------------------------
__global__ __launch_bounds__(256) void conv_f32_bf16(
    const float* __restrict__ in, ushort* __restrict__ out, int n)
{
    int i = (blockIdx.x * 256 + threadIdx.x) * 8;
    if (i >= n) return;
    float4 a = *(const float4*)(in + i);
    float4 b = *(const float4*)(in + i + 4);
    ushort8 o = {f2bf(a.x), f2bf(a.y), f2bf(a.z), f2bf(a.w),
                 f2bf(b.x), f2bf(b.y), f2bf(b.z), f2bf(b.w)};
    *(ushort8*)(out + i) = o;
}

// ---------------------------------------------------------------------------
// f32 [R][C] -> bf16 [C][R] transpose-convert (R,C multiples of 32)
// ---------------------------------------------------------------------------
__global__ __launch_bounds__(256) void transconv(
    const float* __restrict__ in, ushort* __restrict__ out, int R, int C)
{
    __shared__ float t[32][33];
    const int tx = threadIdx.x & 31, ty = threadIdx.x >> 5;
    const int bx = blockIdx.x, by = blockIdx.y;   // C-tile, R-tile
#pragma unroll
    for (int i = 0; i < 4; ++i)
        t[ty + 8 * i][tx] = in[(size_t)(by * 32 + ty + 8 * i) * C + bx * 32 + tx];
    __syncthreads();
#pragma unroll
    for (int i = 0; i < 4; ++i)
        out[(size_t)(bx * 32 + ty + 8 * i) * R + by * 32 + tx] = f2bf(t[tx][ty + 8 * i]);
}

// ---------------------------------------------------------------------------
// C[M,N] = A[M,K] @ BT[N,K]^T + bias, both operands bf16 K-major.
// m97 structure: 128x128 tile, BK=32, 256 thr (4 waves 2x2), 16x16x32 MFMA,
// global_load_lds(16B), XOR-swizzled 16B chunks (2-way banks on ds_read_b128).
// M,N % 128 == 0, K % 32 == 0.
// ---------------------------------------------------------------------------
template<int OUT_BF16, int BIAS_ROW>
__global__ __launch_bounds__(256) void gemm_bt(
    const ushort* __restrict__ A, const ushort* __restrict__ BT,
    const float* __restrict__ bias, void* __restrict__ Cout,
    int M, int N, int K, float oscale)
{
    __shared__ ushort As[128 * 32];
    __shared__ ushort Bs[128 * 32];
    const int tid = threadIdx.x;
    const int w = tid >> 6, lane = tid & 63;
    const int m = lane & 15, quad = lane >> 4;
    const int wr = w >> 1, wc = w & 1;
    const int bx = blockIdx.x, by = blockIdx.y;

    f32x4 acc[4][4];
#pragma unroll
    for (int i = 0; i < 4; ++i)
#pragma unroll
        for (int j = 0; j < 4; ++j)
#pragma unroll
            for (int r = 0; r < 4; ++r) acc[i][j][r] = 0.f;

    // staging: wave w stages rows [w*32, w*32+32) of both tiles (2 issues each)
    const int r_i = lane >> 2;                                  // 0..15
    const int ccl = (lane & 3) ^ ((lane >> 2) & 3) ^ quad;      // swizzled logical chunk
    const ushort* Ag = A  + (size_t)(by * 128 + w * 32 + r_i) * K + ccl * 8;
    const ushort* Bg = BT + (size_t)(bx * 128 + w * 32 + r_i) * K + ccl * 8;
    ushort* AsW = As + w * 1024;
    ushort* BsW = Bs + w * 1024;
    const size_t rowstep = (size_t)16 * K;

    // compute-read offsets: phys chunk = quad ^ swz4(row), swz4 = (m&3)^(m>>2)
    const int phys = (quad ^ (m & 3) ^ (m >> 2)) * 8;
    int aoff[4], boff[4];
#pragma unroll
    for (int i = 0; i < 4; ++i) {
        aoff[i] = (wr * 64 + i * 16 + m) * 32 + phys;
        boff[i] = (wc * 64 + i * 16 + m) * 32 + phys;
    }

    const int kIters = K >> 5;
    for (int kt = 0; kt < kIters; ++kt) {
        __syncthreads();
        gld_lds16(Ag, AsW);
        gld_lds16(Ag + rowstep, AsW + 512);
        gld_lds16(Bg, BsW);
        gld_lds16(Bg + rowstep, BsW + 512);
        Ag += 32; Bg += 32;
        __syncthreads();
        short8 af[4], bf[4];
#pragma unroll
        for (int i = 0; i < 4; ++i) af[i] = *(const short8*)(As + aoff[i]);
#pragma unroll
        for (int i = 0; i < 4; ++i) bf[i] = *(const short8*)(Bs + boff[i]);
#pragma unroll
        for (int i = 0; i < 4; ++i)
#pragma unroll
            for (int j = 0; j < 4; ++j)
                acc[i][j] = __builtin_amdgcn_mfma_f32_16x16x32_bf16(
                    af[i], bf[j], acc[i][j], 0, 0, 0);
    }

    // epilogue: C row = mi*16 + quad*4 + r, col = ni*16 + m
    const int row0 = by * 128 + wr * 64;
    const int col0 = bx * 128 + wc * 64;
#pragma unroll
    for (int i = 0; i < 4; ++i) {
#pragma unroll
        for (int j = 0; j < 4; ++j) {
            const int c = col0 + j * 16 + m;
            float bcol = BIAS_ROW ? 0.f : bias[c];
#pragma unroll
            for (int r = 0; r < 4; ++r) {
                const int rw = row0 + i * 16 + quad * 4 + r;
                float v = acc[i][j][r] + (BIAS_ROW ? bias[rw] : bcol);
                v *= oscale;
                if (OUT_BF16)
                    ((ushort*)Cout)[(size_t)rw * N + c] = f2bf(v);
                else
                    ((float*)Cout)[(size_t)rw * N + c] = v;
            }
        }
    }
}

// ---------------------------------------------------------------------------
// MFMA flash attention v2. qb [2048,1024] bf16 (PRE-SCALED by log2e/64),
// kb [8192,1024] bf16, vT [1024,8192] bf16, out bf16.
// Block = 512 thr (8 waves): wave (wp,wv) = (w>>2, w&3) handles p-rows
// [wp*32,+32) x v-quarter [wv*32,+32) of each 128-v tile.
// S^T = K*Q^T (1 subtile, 4 ksteps); P = exp2(S^T) in regs; PV A-fragment
// rebuilt in-register: per kstep 4x v_cvt_pk_bf16_f32 + 2x
// v_permlane32_swap_b32 (dst-hi <-> src-lo) give words [a0,a1,b0,b1].
// o/l partials over v-quarters combine LINEARLY in epilogue (no max-sub).
// grid = 8b*16h*4pt = 512 blocks -> 2 blocks/CU, 16 waves/CU (4/SIMD).
// ---------------------------------------------------------------------------
__global__ __launch_bounds__(512, 4) void attn_mfma(
    const ushort* __restrict__ qb, const ushort* __restrict__ kb,
    const ushort* __restrict__ vT, ushort* __restrict__ mappedb)
{
    __shared__ ushort Qs[64 * 64];     //  8 KB  [p][k]
    __shared__ ushort Ks[128 * 64];    // 16 KB  [v][k]  (16B-chunk swizzled)
    __shared__ ushort Vs[64 * 128];    // 16 KB  [d][v]  (16B-chunk swizzled)

    const int tid = threadIdx.x;
    const int w = tid >> 6, lane = tid & 63;
    const int l31 = lane & 31, l5 = lane >> 5, quad = lane >> 4;
    const int wp = w >> 2, wv = w & 3;
    const int idx = blockIdx.x;
    const int pt = idx & 3, h = (idx >> 2) & 15, b = idx >> 6;
    const int pbase = b * 256 + pt * 64;

    const int c8 = lane & 7, r8 = lane >> 3, c16 = lane & 15;

    // ---- stage Q once (8 issues of 1KB, one per wave) ----
    {
        const ushort* g = qb + (size_t)(pbase + w * 8 + r8) * 1024 + h * 64 + c8 * 8;
        gld_lds16(g, Qs + w * 512);
    }
    __syncthreads();
    short8 qf[4];
#pragma unroll
    for (int ks = 0; ks < 4; ++ks)
        qf[ks] = *(const short8*)(Qs + (wp * 32 + l31) * 64 + ks * 16 + l5 * 8);

    f32x16 o[2];
#pragma unroll
    for (int dt = 0; dt < 2; ++dt)
#pragma unroll
        for (int r = 0; r < 16; ++r) o[dt][r] = 0.f;
    float lpart = 0.f;

    const int ccK = c8 ^ r8;           // Ks staging logical chunk (swizzle)

    for (int vt = 0; vt < 8192; vt += 128) {
        __syncthreads();
        // ---- stage K (16KB) + V^T (16KB), 2 issues each per wave ----
#pragma unroll
        for (int i = 0; i < 2; ++i) {
            const int t = w * 2 + i;                       // 0..15
            const ushort* gk = kb + (size_t)(vt + t * 8 + r8) * 1024 + h * 64 + ccK * 8;
            gld_lds16(gk, Ks + t * 512);
            const int d_l = t * 4 + quad;
            const int ccV = c16 ^ (d_l & 15);
            const ushort* gv = vT + (size_t)(h * 64 + d_l) * 8192 + vt + ccV * 8;
            gld_lds16(gv, Vs + t * 512);
        }
        __syncthreads();

        // ---- S^T = K * Q^T  (this wave's 32-v subtile, K=64 over 4 ksteps) ----
        f32x16 st;
#pragma unroll
        for (int r = 0; r < 16; ++r) st[r] = 0.f;
        {
            const int row = (wv * 32 + l31) * 64;
            const int sw = l31 & 7;
            __builtin_amdgcn_s_setprio(1);
#pragma unroll
            for (int ks = 0; ks < 4; ++ks) {
                const int ph = ((ks * 2 + l5) ^ sw) * 8;
                short8 kf = *(const short8*)(Ks + row + ph);
                st = __builtin_amdgcn_mfma_f32_32x32x16_bf16(kf, qf[ks], st, 0, 0, 0);
            }
            __builtin_amdgcn_s_setprio(0);
        }

        // ---- P = exp2(S^T) in regs; rebuild PV A-frag; O += P*V ----
        // st reg r holds P^T value at v = (r&3) + 8*(r>>2) + 4*l5 (p = l31).
        // PV kstep k4 (k8 = wv*2+k4) needs lane(p,l5) octet v = 16k4+8*l5+j.
        // a0..b1 = cvt_pk pairs of e[8k4 + 0..7]; permlane32_swap(a,b)
        // (dst-hi <-> src-lo) yields words: a0'=w0, a1'=w1, b0'=w2, b1'=w3.
#pragma unroll
        for (int k4 = 0; k4 < 2; ++k4) {
            float e[8];
#pragma unroll
            for (int t = 0; t < 8; ++t) e[t] = exp2f(st[k4 * 8 + t]);
            lpart += ((e[0] + e[1]) + (e[2] + e[3])) + ((e[4] + e[5]) + (e[6] + e[7]));
            unsigned int a0, a1, b0, b1;
            asm("v_cvt_pk_bf16_f32 %0, %1, %2" : "=v"(a0) : "v"(e[0]), "v"(e[1]));
            asm("v_cvt_pk_bf16_f32 %0, %1, %2" : "=v"(a1) : "v"(e[2]), "v"(e[3]));
            asm("v_cvt_pk_bf16_f32 %0, %1, %2" : "=v"(b0) : "v"(e[4]), "v"(e[5]));
            asm("v_cvt_pk_bf16_f32 %0, %1, %2" : "=v"(b1) : "v"(e[6]), "v"(e[7]));
            asm("v_permlane32_swap_b32 %0, %1" : "+v"(a0), "+v"(b0));
            asm("v_permlane32_swap_b32 %0, %1" : "+v"(a1), "+v"(b1));
            uint4v pfw = {a0, a1, b0, b1};
            short8 pf = __builtin_bit_cast(short8, pfw);
            const int k8 = wv * 2 + k4;
            __builtin_amdgcn_s_setprio(1);
#pragma unroll
            for (int dt = 0; dt < 2; ++dt) {
                const int d_l = dt * 32 + l31;
                const int ph = ((k8 * 2 + l5) ^ (d_l & 15)) * 8;
                short8 vf = *(const short8*)(Vs + d_l * 128 + ph);
                o[dt] = __builtin_amdgcn_mfma_f32_32x32x16_bf16(pf, vf, o[dt], 0, 0, 0);
            }
            __builtin_amdgcn_s_setprio(0);
        }
    }

    // ---- cross-wave (4 v-quarters) linear reduce of o and l via LDS ----
    float* RedA = (float*)Ks;              // 16 KB: [wp][32r][64lane]
    float* RedB = (float*)Vs;              // 16 KB
    float* Lq   = (float*)Qs;              // 8 waves x 64 lanes lpart (2 KB)
    Lq[w * 64 + lane] = lpart;             // Qs dead since prologue
    __syncthreads();                       // all Ks/Vs reads done; safe to reuse
    if (wv >= 2) {
        float* R = (wv == 2) ? RedA : RedB;
#pragma unroll
        for (int dt = 0; dt < 2; ++dt)
#pragma unroll
            for (int r = 0; r < 16; ++r)
                R[wp * 2048 + (dt * 16 + r) * 64 + lane] = o[dt][r];
    }
    __syncthreads();
    if (wv < 2) {
        float* R = (wv == 0) ? RedA : RedB;
#pragma unroll
        for (int dt = 0; dt < 2; ++dt)
#pragma unroll
            for (int r = 0; r < 16; ++r)
                o[dt][r] += R[wp * 2048 + (dt * 16 + r) * 64 + lane];
    }
    __syncthreads();
    if (wv == 1) {
#pragma unroll
        for (int dt = 0; dt < 2; ++dt)
#pragma unroll
            for (int r = 0; r < 16; ++r)
                RedA[wp * 2048 + (dt * 16 + r) * 64 + lane] = o[dt][r];
    }
    __syncthreads();
    if (wv == 0) {
#pragma unroll
        for (int dt = 0; dt < 2; ++dt)
#pragma unroll
            for (int r = 0; r < 16; ++r)
                o[dt][r] += RedA[wp * 2048 + (dt * 16 + r) * 64 + lane];
        float lsum = (Lq[(wp * 4 + 0) * 64 + lane] + Lq[(wp * 4 + 1) * 64 + lane])
                   + (Lq[(wp * 4 + 2) * 64 + lane] + Lq[(wp * 4 + 3) * 64 + lane]);

        // ---- epilogue: normalize by l, write bf16 ----
        float lfull = lsum + __shfl_xor(lsum, 32, 64);
        float rinv = 1.0f / lfull;
#pragma unroll
        for (int r = 0; r < 16; ++r) {
            const int poff = (r & 3) + 8 * (r >> 2) + 4 * l5;
            const float sc = __shfl(rinv, poff, 64);
            const size_t grow = (size_t)(pbase + wp * 32 + poff) * 1024;
#pragma unroll
            for (int dt = 0; dt < 2; ++dt)
                mappedb[grow + h * 64 + dt * 32 + l31] = f2bf(o[dt][r] * sc);
        }
    }
}

// ---------------------------------------------------------------------------
extern "C" void kernel_launch(void* const* d_in, const int* in_sizes, int n_in,
                              void* d_out, int out_size, void* d_ws, size_t ws_size,
                              hipStream_t stream)
{
    const float* query = (const float*)d_in[0];
    const float* key   = (const float*)d_in[1];
    const float* value = (const float*)d_in[2];
    const float* Wq    = (const float*)d_in[3];
    const float* bq    = (const float*)d_in[4];
    const float* Wk    = (const float*)d_in[5];
    const float* bk    = (const float*)d_in[6];
    const float* Wv    = (const float*)d_in[7];
    const float* bv    = (const float*)d_in[8];
    const float* Wo    = (const float*)d_in[9];
    const float* bo    = (const float*)d_in[10];
    float* out = (float*)d_out;

    // ws layout (<= 80 MB): tmpb 64MB | wslot 8MB | queryb 4MB | qb 4MB
    // mappedb aliases tmpb[0:4MB) (tmp dead after vproj).
    // d_out (32MB) used as scratch for kb/vT, fully overwritten by final gemm.
    char* ws = (char*)d_ws;
    ushort* tmpb    = (ushort*)ws;
    ushort* wslot   = (ushort*)(ws + (64ull << 20));
    ushort* queryb  = (ushort*)(ws + (72ull << 20));
    ushort* qb      = (ushort*)(ws + (76ull << 20));
    ushort* mappedb = (ushort*)ws;
    ushort* kb      = (ushort*)d_out;
    ushort* vT      = (ushort*)((char*)d_out + (16ull << 20));

    const float QSCALE = 1.4426950408889634f / 64.0f;   // log2(e)/64 folded into q

    // k-projection: kb[8192,1024] = key @ Wk + bk
    conv_f32_bf16<<<16384, 256, 0, stream>>>(key, tmpb, 8192 * 4096);
    transconv<<<dim3(32, 128), 256, 0, stream>>>(Wk, wslot, 4096, 1024);
    gemm_bt<1, 0><<<dim3(8, 64), 256, 0, stream>>>(tmpb, wslot, bk, kb,
                                                   8192, 1024, 4096, 1.0f);
    // v-projection, TRANSPOSED: vT[1024,8192] = WvT @ value^T  (row bias bv)
    conv_f32_bf16<<<16384, 256, 0, stream>>>(value, tmpb, 8192 * 4096);
    transconv<<<dim3(32, 128), 256, 0, stream>>>(Wv, wslot, 4096, 1024);
    gemm_bt<1, 1><<<dim3(64, 8), 256, 0, stream>>>(wslot, tmpb, bv, vT,
                                                   1024, 8192, 4096, 1.0f);
    // q-projection (pre-scaled): qb[2048,1024] = (query @ Wq + bq) * QSCALE
    conv_f32_bf16<<<1024, 256, 0, stream>>>(query, queryb, 2048 * 1024);
    transconv<<<dim3(32, 32), 256, 0, stream>>>(Wq, wslot, 1024, 1024);
    gemm_bt<1, 0><<<dim3(8, 16), 256, 0, stream>>>(queryb, wslot, bq, qb,
                                                   2048, 1024, 1024, QSCALE);
    // attention -> mappedb [2048,1024] bf16  (8-wave blocks, in-register P)
    attn_mfma<<<512, 512, 0, stream>>>(qb, kb, vT, mappedb);
    // output projection (fp32 out): out[2048,4096] = mapped @ Wo + bo
    transconv<<<dim3(128, 32), 256, 0, stream>>>(Wo, wslot, 1024, 4096);
    gemm_bt<0, 0><<<dim3(32, 16), 256, 0, stream>>>(mappedb, wslot, bo, out,
                                                    2048, 4096, 1024, 1.0f);
}

// Round 5
// 707.660 us; speedup vs baseline: 1.1579x; 1.0076x over previous
//
#include <hip/hip_runtime.h>

// ---------------------------------------------------------------------------
// Mapping_64725157151005 — bf16 MFMA pipeline.
// B=8, P=256, DM=1024, DL=4096, H=16, DK=64, V=8192.
// Round 4: attn v3 — double-buffered K/V staging (2-phase pipeline, T3/T4):
// issue next-tile global_load_lds BEFORE the counted s_waitcnt vmcnt(4) +
// raw s_barrier (no full vmcnt(0) drain in the main loop). LDS 40->72 KB,
// still 2 blocks/CU (144 <= 160). Prefetch wraps at t=63 (harmless).
// ---------------------------------------------------------------------------

typedef __attribute__((ext_vector_type(8)))  short          short8;
typedef __attribute__((ext_vector_type(4)))  float          f32x4;
typedef __attribute__((ext_vector_type(16))) float          f32x16;
typedef __attribute__((ext_vector_type(8)))  unsigned short ushort8;
typedef __attribute__((ext_vector_type(4)))  unsigned int   uint4v;

__device__ __forceinline__ unsigned short f2bf(float f) {
    unsigned int u = __builtin_bit_cast(unsigned int, f);
    u += 0x7fffu + ((u >> 16) & 1u);          // RNE
    return (unsigned short)(u >> 16);
}

// async global->LDS, 16B per lane; LDS dst = wave-uniform base + lane*16
__device__ __forceinline__ void gld_lds16(const ushort* g, ushort* l) {
    __builtin_amdgcn_global_load_lds(
        (const __attribute__((address_space(1))) void*)g,
        (__attribute__((address_space(3))) void*)l, 16, 0, 0);
}

// ---------------------------------------------------------------------------
// f32 -> bf16 elementwise convert
// ---------------------------------------------------------------------------
__global__ __launch_bounds__(256) void conv_f32_bf16(
    const float* __restrict__ in, ushort* __restrict__ out, int n)
{
    int i = (blockIdx.x * 256 + threadIdx.x) * 8;
    if (i >= n) return;
    float4 a = *(const float4*)(in + i);
    float4 b = *(const float4*)(in + i + 4);
    ushort8 o = {f2bf(a.x), f2bf(a.y), f2bf(a.z), f2bf(a.w),
                 f2bf(b.x), f2bf(b.y), f2bf(b.z), f2bf(b.w)};
    *(ushort8*)(out + i) = o;
}

// ---------------------------------------------------------------------------
// f32 [R][C] -> bf16 [C][R] transpose-convert (R,C multiples of 32)
// ---------------------------------------------------------------------------
__global__ __launch_bounds__(256) void transconv(
    const float* __restrict__ in, ushort* __restrict__ out, int R, int C)
{
    __shared__ float t[32][33];
    const int tx = threadIdx.x & 31, ty = threadIdx.x >> 5;
    const int bx = blockIdx.x, by = blockIdx.y;   // C-tile, R-tile
#pragma unroll
    for (int i = 0; i < 4; ++i)
        t[ty + 8 * i][tx] = in[(size_t)(by * 32 + ty + 8 * i) * C + bx * 32 + tx];
    __syncthreads();
#pragma unroll
    for (int i = 0; i < 4; ++i)
        out[(size_t)(bx * 32 + ty + 8 * i) * R + by * 32 + tx] = f2bf(t[tx][ty + 8 * i]);
}

// ---------------------------------------------------------------------------
// C[M,N] = A[M,K] @ BT[N,K]^T + bias, both operands bf16 K-major.
// m97 structure: 128x128 tile, BK=32, 256 thr (4 waves 2x2), 16x16x32 MFMA,
// global_load_lds(16B), XOR-swizzled 16B chunks (2-way banks on ds_read_b128).
// M,N % 128 == 0, K % 32 == 0.
// ---------------------------------------------------------------------------
template<int OUT_BF16, int BIAS_ROW>
__global__ __launch_bounds__(256) void gemm_bt(
    const ushort* __restrict__ A, const ushort* __restrict__ BT,
    const float* __restrict__ bias, void* __restrict__ Cout,
    int M, int N, int K, float oscale)
{
    __shared__ ushort As[128 * 32];
    __shared__ ushort Bs[128 * 32];
    const int tid = threadIdx.x;
    const int w = tid >> 6, lane = tid & 63;
    const int m = lane & 15, quad = lane >> 4;
    const int wr = w >> 1, wc = w & 1;
    const int bx = blockIdx.x, by = blockIdx.y;

    f32x4 acc[4][4];
#pragma unroll
    for (int i = 0; i < 4; ++i)
#pragma unroll
        for (int j = 0; j < 4; ++j)
#pragma unroll
            for (int r = 0; r < 4; ++r) acc[i][j][r] = 0.f;

    // staging: wave w stages rows [w*32, w*32+32) of both tiles (2 issues each)
    const int r_i = lane >> 2;                                  // 0..15
    const int ccl = (lane & 3) ^ ((lane >> 2) & 3) ^ quad;      // swizzled logical chunk
    const ushort* Ag = A  + (size_t)(by * 128 + w * 32 + r_i) * K + ccl * 8;
    const ushort* Bg = BT + (size_t)(bx * 128 + w * 32 + r_i) * K + ccl * 8;
    ushort* AsW = As + w * 1024;
    ushort* BsW = Bs + w * 1024;
    const size_t rowstep = (size_t)16 * K;

    // compute-read offsets: phys chunk = quad ^ swz4(row), swz4 = (m&3)^(m>>2)
    const int phys = (quad ^ (m & 3) ^ (m >> 2)) * 8;
    int aoff[4], boff[4];
#pragma unroll
    for (int i = 0; i < 4; ++i) {
        aoff[i] = (wr * 64 + i * 16 + m) * 32 + phys;
        boff[i] = (wc * 64 + i * 16 + m) * 32 + phys;
    }

    const int kIters = K >> 5;
    for (int kt = 0; kt < kIters; ++kt) {
        __syncthreads();
        gld_lds16(Ag, AsW);
        gld_lds16(Ag + rowstep, AsW + 512);
        gld_lds16(Bg, BsW);
        gld_lds16(Bg + rowstep, BsW + 512);
        Ag += 32; Bg += 32;
        __syncthreads();
        short8 af[4], bf[4];
#pragma unroll
        for (int i = 0; i < 4; ++i) af[i] = *(const short8*)(As + aoff[i]);
#pragma unroll
        for (int i = 0; i < 4; ++i) bf[i] = *(const short8*)(Bs + boff[i]);
#pragma unroll
        for (int i = 0; i < 4; ++i)
#pragma unroll
            for (int j = 0; j < 4; ++j)
                acc[i][j] = __builtin_amdgcn_mfma_f32_16x16x32_bf16(
                    af[i], bf[j], acc[i][j], 0, 0, 0);
    }

    // epilogue: C row = mi*16 + quad*4 + r, col = ni*16 + m
    const int row0 = by * 128 + wr * 64;
    const int col0 = bx * 128 + wc * 64;
#pragma unroll
    for (int i = 0; i < 4; ++i) {
#pragma unroll
        for (int j = 0; j < 4; ++j) {
            const int c = col0 + j * 16 + m;
            float bcol = BIAS_ROW ? 0.f : bias[c];
#pragma unroll
            for (int r = 0; r < 4; ++r) {
                const int rw = row0 + i * 16 + quad * 4 + r;
                float v = acc[i][j][r] + (BIAS_ROW ? bias[rw] : bcol);
                v *= oscale;
                if (OUT_BF16)
                    ((ushort*)Cout)[(size_t)rw * N + c] = f2bf(v);
                else
                    ((float*)Cout)[(size_t)rw * N + c] = v;
            }
        }
    }
}

// ---------------------------------------------------------------------------
// MFMA flash attention v3. qb [2048,1024] bf16 (PRE-SCALED by log2e/64),
// kb [8192,1024] bf16, vT [1024,8192] bf16, out bf16.
// Block = 512 thr (8 waves): wave (wp,wv) = (w>>2, w&3) handles p-rows
// [wp*32,+32) x v-quarter [wv*32,+32) of each 128-v tile.
// DOUBLE-BUFFERED K/V staging: next tile's global_load_lds issued before a
// counted s_waitcnt vmcnt(4) + raw s_barrier (prefetch stays in flight
// across the barrier). P in registers (cvt_pk + permlane32_swap).
// o/l partials over v-quarters combine LINEARLY in epilogue (no max-sub).
// grid = 512 blocks -> 2 blocks/CU (144KB LDS), 16 waves/CU (4/SIMD).
// ---------------------------------------------------------------------------
__global__ __launch_bounds__(512, 4) void attn_mfma(
    const ushort* __restrict__ qb, const ushort* __restrict__ kb,
    const ushort* __restrict__ vT, ushort* __restrict__ mappedb)
{
    __shared__ ushort Qs[64 * 64];        //  8 KB  [p][k]
    __shared__ ushort Ks[2][128 * 64];    // 32 KB  [v][k]  (16B-chunk swizzled)
    __shared__ ushort Vs[2][64 * 128];    // 32 KB  [d][v]  (16B-chunk swizzled)

    const int tid = threadIdx.x;
    const int w = tid >> 6, lane = tid & 63;
    const int l31 = lane & 31, l5 = lane >> 5, quad = lane >> 4;
    const int wp = w >> 2, wv = w & 3;
    const int idx = blockIdx.x;
    const int pt = idx & 3, h = (idx >> 2) & 15, b = idx >> 6;
    const int pbase = b * 256 + pt * 64;

    const int c8 = lane & 7, r8 = lane >> 3, c16 = lane & 15;
    const int ccK = c8 ^ r8;              // Ks staging logical chunk (swizzle)

    // per-wave staging addresses (tile offset added per iteration)
    const int t0 = w * 2, t1 = w * 2 + 1;
    const ushort* gk0 = kb + (size_t)(t0 * 8 + r8) * 1024 + h * 64 + ccK * 8;
    const ushort* gk1 = kb + (size_t)(t1 * 8 + r8) * 1024 + h * 64 + ccK * 8;
    const int d0 = t0 * 4 + quad, d1 = t1 * 4 + quad;
    const ushort* gv0 = vT + (size_t)(h * 64 + d0) * 8192 + ((c16 ^ (d0 & 15)) * 8);
    const ushort* gv1 = vT + (size_t)(h * 64 + d1) * 8192 + ((c16 ^ (d1 & 15)) * 8);

    // ---- prologue: stage Q (1 issue/wave) + tile 0 into buf 0 ----
    {
        const ushort* g = qb + (size_t)(pbase + w * 8 + r8) * 1024 + h * 64 + c8 * 8;
        gld_lds16(g, Qs + w * 512);
    }
    gld_lds16(gk0, Ks[0] + t0 * 512);
    gld_lds16(gk1, Ks[0] + t1 * 512);
    gld_lds16(gv0, Vs[0] + t0 * 512);
    gld_lds16(gv1, Vs[0] + t1 * 512);
    asm volatile("s_waitcnt vmcnt(4)" ::: "memory");   // Q (oldest) landed
    __builtin_amdgcn_s_barrier();                      // all waves' Q in LDS
    __builtin_amdgcn_sched_barrier(0);
    short8 qf[4];
#pragma unroll
    for (int ks = 0; ks < 4; ++ks)
        qf[ks] = *(const short8*)(Qs + (wp * 32 + l31) * 64 + ks * 16 + l5 * 8);

    f32x16 o[2];
#pragma unroll
    for (int dt = 0; dt < 2; ++dt)
#pragma unroll
        for (int r = 0; r < 16; ++r) o[dt][r] = 0.f;
    float lpart = 0.f;

    for (int t = 0; t < 64; ++t) {
        const int cur = t & 1;
        // ---- prefetch tile t+1 (wraps to 0 at t=63; harmless, unused) ----
        {
            const size_t koff = (size_t)(((t + 1) & 63) * 128) * 1024;
            const size_t voff = (size_t)(((t + 1) & 63) * 128);
            ushort* KsN = Ks[cur ^ 1];
            ushort* VsN = Vs[cur ^ 1];
            gld_lds16(gk0 + koff, KsN + t0 * 512);
            gld_lds16(gk1 + koff, KsN + t1 * 512);
            gld_lds16(gv0 + voff, VsN + t0 * 512);
            gld_lds16(gv1 + voff, VsN + t1 * 512);
        }
        // ---- wait tile t's 4 loads (counted, prefetch stays in flight) ----
        asm volatile("s_waitcnt vmcnt(4)" ::: "memory");
        __builtin_amdgcn_s_barrier();
        __builtin_amdgcn_sched_barrier(0);

        const ushort* KsC = Ks[cur];
        const ushort* VsC = Vs[cur];

        // ---- S^T = K * Q^T  (this wave's 32-v subtile, K=64 over 4 ksteps) ----
        f32x16 st;
#pragma unroll
        for (int r = 0; r < 16; ++r) st[r] = 0.f;
        {
            const int row = (wv * 32 + l31) * 64;
            const int sw = l31 & 7;
            __builtin_amdgcn_s_setprio(1);
#pragma unroll
            for (int ks = 0; ks < 4; ++ks) {
                const int ph = ((ks * 2 + l5) ^ sw) * 8;
                short8 kf = *(const short8*)(KsC + row + ph);
                st = __builtin_amdgcn_mfma_f32_32x32x16_bf16(kf, qf[ks], st, 0, 0, 0);
            }
            __builtin_amdgcn_s_setprio(0);
        }

        // ---- P = exp2(S^T) in regs; rebuild PV A-frag; O += P*V ----
        // st reg r holds P^T value at v = (r&3) + 8*(r>>2) + 4*l5 (p = l31).
        // PV kstep k4 (k8 = wv*2+k4) needs lane(p,l5) octet v = 16k4+8*l5+j.
        // a0..b1 = cvt_pk pairs of e[8k4 + 0..7]; permlane32_swap(a,b)
        // (dst-hi <-> src-lo) yields words: a0'=w0, a1'=w1, b0'=w2, b1'=w3.
#pragma unroll
        for (int k4 = 0; k4 < 2; ++k4) {
            float e[8];
#pragma unroll
            for (int tt = 0; tt < 8; ++tt) e[tt] = exp2f(st[k4 * 8 + tt]);
            lpart += ((e[0] + e[1]) + (e[2] + e[3])) + ((e[4] + e[5]) + (e[6] + e[7]));
            unsigned int a0, a1, b0, b1;
            asm("v_cvt_pk_bf16_f32 %0, %1, %2" : "=v"(a0) : "v"(e[0]), "v"(e[1]));
            asm("v_cvt_pk_bf16_f32 %0, %1, %2" : "=v"(a1) : "v"(e[2]), "v"(e[3]));
            asm("v_cvt_pk_bf16_f32 %0, %1, %2" : "=v"(b0) : "v"(e[4]), "v"(e[5]));
            asm("v_cvt_pk_bf16_f32 %0, %1, %2" : "=v"(b1) : "v"(e[6]), "v"(e[7]));
            asm("v_permlane32_swap_b32 %0, %1" : "+v"(a0), "+v"(b0));
            asm("v_permlane32_swap_b32 %0, %1" : "+v"(a1), "+v"(b1));
            uint4v pfw = {a0, a1, b0, b1};
            short8 pf = __builtin_bit_cast(short8, pfw);
            const int k8 = wv * 2 + k4;
            __builtin_amdgcn_s_setprio(1);
#pragma unroll
            for (int dt = 0; dt < 2; ++dt) {
                const int d_l = dt * 32 + l31;
                const int ph = ((k8 * 2 + l5) ^ (d_l & 15)) * 8;
                short8 vf = *(const short8*)(VsC + d_l * 128 + ph);
                o[dt] = __builtin_amdgcn_mfma_f32_32x32x16_bf16(pf, vf, o[dt], 0, 0, 0);
            }
            __builtin_amdgcn_s_setprio(0);
        }
        __builtin_amdgcn_sched_barrier(0);
        __builtin_amdgcn_s_barrier();   // all waves done reading buf[cur]
    }

    // ---- cross-wave (4 v-quarters) linear reduce of o and l via LDS ----
    float* RedA = (float*)Ks[0];           // 16 KB used: [wp][32r][64lane]
    float* RedB = (float*)Vs[0];           // 16 KB used
    float* Lq   = (float*)Qs;              // 8 waves x 64 lanes lpart (2 KB)
    Lq[w * 64 + lane] = lpart;             // Qs dead since prologue
    __syncthreads();   // full vmcnt(0)+lgkmcnt(0) drain: wrap-prefetch DMA done
    if (wv >= 2) {
        float* R = (wv == 2) ? RedA : RedB;
#pragma unroll
        for (int dt = 0; dt < 2; ++dt)
#pragma unroll
            for (int r = 0; r < 16; ++r)
                R[wp * 2048 + (dt * 16 + r) * 64 + lane] = o[dt][r];
    }
    __syncthreads();
    if (wv < 2) {
        float* R = (wv == 0) ? RedA : RedB;
#pragma unroll
        for (int dt = 0; dt < 2; ++dt)
#pragma unroll
            for (int r = 0; r < 16; ++r)
                o[dt][r] += R[wp * 2048 + (dt * 16 + r) * 64 + lane];
    }
    __syncthreads();
    if (wv == 1) {
#pragma unroll
        for (int dt = 0; dt < 2; ++dt)
#pragma unroll
            for (int r = 0; r < 16; ++r)
                RedA[wp * 2048 + (dt * 16 + r) * 64 + lane] = o[dt][r];
    }
    __syncthreads();
    if (wv == 0) {
#pragma unroll
        for (int dt = 0; dt < 2; ++dt)
#pragma unroll
            for (int r = 0; r < 16; ++r)
                o[dt][r] += RedA[wp * 2048 + (dt * 16 + r) * 64 + lane];
        float lsum = (Lq[(wp * 4 + 0) * 64 + lane] + Lq[(wp * 4 + 1) * 64 + lane])
                   + (Lq[(wp * 4 + 2) * 64 + lane] + Lq[(wp * 4 + 3) * 64 + lane]);

        // ---- epilogue: normalize by l, write bf16 ----
        float lfull = lsum + __shfl_xor(lsum, 32, 64);
        float rinv = 1.0f / lfull;
#pragma unroll
        for (int r = 0; r < 16; ++r) {
            const int poff = (r & 3) + 8 * (r >> 2) + 4 * l5;
            const float sc = __shfl(rinv, poff, 64);
            const size_t grow = (size_t)(pbase + wp * 32 + poff) * 1024;
#pragma unroll
            for (int dt = 0; dt < 2; ++dt)
                mappedb[grow + h * 64 + dt * 32 + l31] = f2bf(o[dt][r] * sc);
        }
    }
}

// ---------------------------------------------------------------------------
extern "C" void kernel_launch(void* const* d_in, const int* in_sizes, int n_in,
                              void* d_out, int out_size, void* d_ws, size_t ws_size,
                              hipStream_t stream)
{
    const float* query = (const float*)d_in[0];
    const float* key   = (const float*)d_in[1];
    const float* value = (const float*)d_in[2];
    const float* Wq    = (const float*)d_in[3];
    const float* bq    = (const float*)d_in[4];
    const float* Wk    = (const float*)d_in[5];
    const float* bk    = (const float*)d_in[6];
    const float* Wv    = (const float*)d_in[7];
    const float* bv    = (const float*)d_in[8];
    const float* Wo    = (const float*)d_in[9];
    const float* bo    = (const float*)d_in[10];
    float* out = (float*)d_out;

    // ws layout (<= 80 MB): tmpb 64MB | wslot 8MB | queryb 4MB | qb 4MB
    // mappedb aliases tmpb[0:4MB) (tmp dead after vproj).
    // d_out (32MB) used as scratch for kb/vT, fully overwritten by final gemm.
    char* ws = (char*)d_ws;
    ushort* tmpb    = (ushort*)ws;
    ushort* wslot   = (ushort*)(ws + (64ull << 20));
    ushort* queryb  = (ushort*)(ws + (72ull << 20));
    ushort* qb      = (ushort*)(ws + (76ull << 20));
    ushort* mappedb = (ushort*)ws;
    ushort* kb      = (ushort*)d_out;
    ushort* vT      = (ushort*)((char*)d_out + (16ull << 20));

    const float QSCALE = 1.4426950408889634f / 64.0f;   // log2(e)/64 folded into q

    // k-projection: kb[8192,1024] = key @ Wk + bk
    conv_f32_bf16<<<16384, 256, 0, stream>>>(key, tmpb, 8192 * 4096);
    transconv<<<dim3(32, 128), 256, 0, stream>>>(Wk, wslot, 4096, 1024);
    gemm_bt<1, 0><<<dim3(8, 64), 256, 0, stream>>>(tmpb, wslot, bk, kb,
                                                   8192, 1024, 4096, 1.0f);
    // v-projection, TRANSPOSED: vT[1024,8192] = WvT @ value^T  (row bias bv)
    conv_f32_bf16<<<16384, 256, 0, stream>>>(value, tmpb, 8192 * 4096);
    transconv<<<dim3(32, 128), 256, 0, stream>>>(Wv, wslot, 4096, 1024);
    gemm_bt<1, 1><<<dim3(64, 8), 256, 0, stream>>>(wslot, tmpb, bv, vT,
                                                   1024, 8192, 4096, 1.0f);
    // q-projection (pre-scaled): qb[2048,1024] = (query @ Wq + bq) * QSCALE
    conv_f32_bf16<<<1024, 256, 0, stream>>>(query, queryb, 2048 * 1024);
    transconv<<<dim3(32, 32), 256, 0, stream>>>(Wq, wslot, 1024, 1024);
    gemm_bt<1, 0><<<dim3(8, 16), 256, 0, stream>>>(queryb, wslot, bq, qb,
                                                   2048, 1024, 1024, QSCALE);
    // attention -> mappedb [2048,1024] bf16  (8 waves, dbuf K/V, in-reg P)
    attn_mfma<<<512, 512, 0, stream>>>(qb, kb, vT, mappedb);
    // output projection (fp32 out): out[2048,4096] = mapped @ Wo + bo
    transconv<<<dim3(128, 32), 256, 0, stream>>>(Wo, wslot, 1024, 4096);
    gemm_bt<0, 0><<<dim3(32, 16), 256, 0, stream>>>(mappedb, wslot, bo, out,
                                                    2048, 4096, 1024, 1.0f);
}

// Round 6
// 687.879 us; speedup vs baseline: 1.1911x; 1.0288x over previous
//
#include <hip/hip_runtime.h>

// ---------------------------------------------------------------------------
// Mapping_64725157151005 — bf16 MFMA pipeline.
// B=8, P=256, DM=1024, DL=4096, H=16, DK=64, V=8192.
// Round 5: attn v3.1 — exp2f -> __builtin_amdgcn_exp2f (bare v_exp_f32;
// OCML exp2f carries ~6-8 VALU of denorm/range guards per call that were
// ~40% of attn's VALU issue). No other changes.
// ---------------------------------------------------------------------------

typedef __attribute__((ext_vector_type(8)))  short          short8;
typedef __attribute__((ext_vector_type(4)))  float          f32x4;
typedef __attribute__((ext_vector_type(16))) float          f32x16;
typedef __attribute__((ext_vector_type(8)))  unsigned short ushort8;
typedef __attribute__((ext_vector_type(4)))  unsigned int   uint4v;

__device__ __forceinline__ unsigned short f2bf(float f) {
    unsigned int u = __builtin_bit_cast(unsigned int, f);
    u += 0x7fffu + ((u >> 16) & 1u);          // RNE
    return (unsigned short)(u >> 16);
}

// async global->LDS, 16B per lane; LDS dst = wave-uniform base + lane*16
__device__ __forceinline__ void gld_lds16(const ushort* g, ushort* l) {
    __builtin_amdgcn_global_load_lds(
        (const __attribute__((address_space(1))) void*)g,
        (__attribute__((address_space(3))) void*)l, 16, 0, 0);
}

// ---------------------------------------------------------------------------
// f32 -> bf16 elementwise convert
// ---------------------------------------------------------------------------
__global__ __launch_bounds__(256) void conv_f32_bf16(
    const float* __restrict__ in, ushort* __restrict__ out, int n)
{
    int i = (blockIdx.x * 256 + threadIdx.x) * 8;
    if (i >= n) return;
    float4 a = *(const float4*)(in + i);
    float4 b = *(const float4*)(in + i + 4);
    ushort8 o = {f2bf(a.x), f2bf(a.y), f2bf(a.z), f2bf(a.w),
                 f2bf(b.x), f2bf(b.y), f2bf(b.z), f2bf(b.w)};
    *(ushort8*)(out + i) = o;
}

// ---------------------------------------------------------------------------
// f32 [R][C] -> bf16 [C][R] transpose-convert (R,C multiples of 32)
// ---------------------------------------------------------------------------
__global__ __launch_bounds__(256) void transconv(
    const float* __restrict__ in, ushort* __restrict__ out, int R, int C)
{
    __shared__ float t[32][33];
    const int tx = threadIdx.x & 31, ty = threadIdx.x >> 5;
    const int bx = blockIdx.x, by = blockIdx.y;   // C-tile, R-tile
#pragma unroll
    for (int i = 0; i < 4; ++i)
        t[ty + 8 * i][tx] = in[(size_t)(by * 32 + ty + 8 * i) * C + bx * 32 + tx];
    __syncthreads();
#pragma unroll
    for (int i = 0; i < 4; ++i)
        out[(size_t)(bx * 32 + ty + 8 * i) * R + by * 32 + tx] = f2bf(t[tx][ty + 8 * i]);
}

// ---------------------------------------------------------------------------
// C[M,N] = A[M,K] @ BT[N,K]^T + bias, both operands bf16 K-major.
// m97 structure: 128x128 tile, BK=32, 256 thr (4 waves 2x2), 16x16x32 MFMA,
// global_load_lds(16B), XOR-swizzled 16B chunks (2-way banks on ds_read_b128).
// M,N % 128 == 0, K % 32 == 0.
// ---------------------------------------------------------------------------
template<int OUT_BF16, int BIAS_ROW>
__global__ __launch_bounds__(256) void gemm_bt(
    const ushort* __restrict__ A, const ushort* __restrict__ BT,
    const float* __restrict__ bias, void* __restrict__ Cout,
    int M, int N, int K, float oscale)
{
    __shared__ ushort As[128 * 32];
    __shared__ ushort Bs[128 * 32];
    const int tid = threadIdx.x;
    const int w = tid >> 6, lane = tid & 63;
    const int m = lane & 15, quad = lane >> 4;
    const int wr = w >> 1, wc = w & 1;
    const int bx = blockIdx.x, by = blockIdx.y;

    f32x4 acc[4][4];
#pragma unroll
    for (int i = 0; i < 4; ++i)
#pragma unroll
        for (int j = 0; j < 4; ++j)
#pragma unroll
            for (int r = 0; r < 4; ++r) acc[i][j][r] = 0.f;

    // staging: wave w stages rows [w*32, w*32+32) of both tiles (2 issues each)
    const int r_i = lane >> 2;                                  // 0..15
    const int ccl = (lane & 3) ^ ((lane >> 2) & 3) ^ quad;      // swizzled logical chunk
    const ushort* Ag = A  + (size_t)(by * 128 + w * 32 + r_i) * K + ccl * 8;
    const ushort* Bg = BT + (size_t)(bx * 128 + w * 32 + r_i) * K + ccl * 8;
    ushort* AsW = As + w * 1024;
    ushort* BsW = Bs + w * 1024;
    const size_t rowstep = (size_t)16 * K;

    // compute-read offsets: phys chunk = quad ^ swz4(row), swz4 = (m&3)^(m>>2)
    const int phys = (quad ^ (m & 3) ^ (m >> 2)) * 8;
    int aoff[4], boff[4];
#pragma unroll
    for (int i = 0; i < 4; ++i) {
        aoff[i] = (wr * 64 + i * 16 + m) * 32 + phys;
        boff[i] = (wc * 64 + i * 16 + m) * 32 + phys;
    }

    const int kIters = K >> 5;
    for (int kt = 0; kt < kIters; ++kt) {
        __syncthreads();
        gld_lds16(Ag, AsW);
        gld_lds16(Ag + rowstep, AsW + 512);
        gld_lds16(Bg, BsW);
        gld_lds16(Bg + rowstep, BsW + 512);
        Ag += 32; Bg += 32;
        __syncthreads();
        short8 af[4], bf[4];
#pragma unroll
        for (int i = 0; i < 4; ++i) af[i] = *(const short8*)(As + aoff[i]);
#pragma unroll
        for (int i = 0; i < 4; ++i) bf[i] = *(const short8*)(Bs + boff[i]);
#pragma unroll
        for (int i = 0; i < 4; ++i)
#pragma unroll
            for (int j = 0; j < 4; ++j)
                acc[i][j] = __builtin_amdgcn_mfma_f32_16x16x32_bf16(
                    af[i], bf[j], acc[i][j], 0, 0, 0);
    }

    // epilogue: C row = mi*16 + quad*4 + r, col = ni*16 + m
    const int row0 = by * 128 + wr * 64;
    const int col0 = bx * 128 + wc * 64;
#pragma unroll
    for (int i = 0; i < 4; ++i) {
#pragma unroll
        for (int j = 0; j < 4; ++j) {
            const int c = col0 + j * 16 + m;
            float bcol = BIAS_ROW ? 0.f : bias[c];
#pragma unroll
            for (int r = 0; r < 4; ++r) {
                const int rw = row0 + i * 16 + quad * 4 + r;
                float v = acc[i][j][r] + (BIAS_ROW ? bias[rw] : bcol);
                v *= oscale;
                if (OUT_BF16)
                    ((ushort*)Cout)[(size_t)rw * N + c] = f2bf(v);
                else
                    ((float*)Cout)[(size_t)rw * N + c] = v;
            }
        }
    }
}

// ---------------------------------------------------------------------------
// MFMA flash attention v3.1. qb [2048,1024] bf16 (PRE-SCALED by log2e/64),
// kb [8192,1024] bf16, vT [1024,8192] bf16, out bf16.
// Block = 512 thr (8 waves): wave (wp,wv) = (w>>2, w&3) handles p-rows
// [wp*32,+32) x v-quarter [wv*32,+32) of each 128-v tile.
// DOUBLE-BUFFERED K/V staging: next tile's global_load_lds issued before a
// counted s_waitcnt vmcnt(4) + raw s_barrier (prefetch stays in flight
// across the barrier). P in registers (cvt_pk + permlane32_swap); exp2 via
// __builtin_amdgcn_exp2f (bare v_exp_f32).
// o/l partials over v-quarters combine LINEARLY in epilogue (no max-sub).
// grid = 512 blocks -> 2 blocks/CU (144KB LDS), 16 waves/CU (4/SIMD).
// ---------------------------------------------------------------------------
__global__ __launch_bounds__(512, 4) void attn_mfma(
    const ushort* __restrict__ qb, const ushort* __restrict__ kb,
    const ushort* __restrict__ vT, ushort* __restrict__ mappedb)
{
    __shared__ ushort Qs[64 * 64];        //  8 KB  [p][k]
    __shared__ ushort Ks[2][128 * 64];    // 32 KB  [v][k]  (16B-chunk swizzled)
    __shared__ ushort Vs[2][64 * 128];    // 32 KB  [d][v]  (16B-chunk swizzled)

    const int tid = threadIdx.x;
    const int w = tid >> 6, lane = tid & 63;
    const int l31 = lane & 31, l5 = lane >> 5, quad = lane >> 4;
    const int wp = w >> 2, wv = w & 3;
    const int idx = blockIdx.x;
    const int pt = idx & 3, h = (idx >> 2) & 15, b = idx >> 6;
    const int pbase = b * 256 + pt * 64;

    const int c8 = lane & 7, r8 = lane >> 3, c16 = lane & 15;
    const int ccK = c8 ^ r8;              // Ks staging logical chunk (swizzle)

    // per-wave staging addresses (tile offset added per iteration)
    const int t0 = w * 2, t1 = w * 2 + 1;
    const ushort* gk0 = kb + (size_t)(t0 * 8 + r8) * 1024 + h * 64 + ccK * 8;
    const ushort* gk1 = kb + (size_t)(t1 * 8 + r8) * 1024 + h * 64 + ccK * 8;
    const int d0 = t0 * 4 + quad, d1 = t1 * 4 + quad;
    const ushort* gv0 = vT + (size_t)(h * 64 + d0) * 8192 + ((c16 ^ (d0 & 15)) * 8);
    const ushort* gv1 = vT + (size_t)(h * 64 + d1) * 8192 + ((c16 ^ (d1 & 15)) * 8);

    // ---- prologue: stage Q (1 issue/wave) + tile 0 into buf 0 ----
    {
        const ushort* g = qb + (size_t)(pbase + w * 8 + r8) * 1024 + h * 64 + c8 * 8;
        gld_lds16(g, Qs + w * 512);
    }
    gld_lds16(gk0, Ks[0] + t0 * 512);
    gld_lds16(gk1, Ks[0] + t1 * 512);
    gld_lds16(gv0, Vs[0] + t0 * 512);
    gld_lds16(gv1, Vs[0] + t1 * 512);
    asm volatile("s_waitcnt vmcnt(4)" ::: "memory");   // Q (oldest) landed
    __builtin_amdgcn_s_barrier();                      // all waves' Q in LDS
    __builtin_amdgcn_sched_barrier(0);
    short8 qf[4];
#pragma unroll
    for (int ks = 0; ks < 4; ++ks)
        qf[ks] = *(const short8*)(Qs + (wp * 32 + l31) * 64 + ks * 16 + l5 * 8);

    f32x16 o[2];
#pragma unroll
    for (int dt = 0; dt < 2; ++dt)
#pragma unroll
        for (int r = 0; r < 16; ++r) o[dt][r] = 0.f;
    float lpart = 0.f;

    for (int t = 0; t < 64; ++t) {
        const int cur = t & 1;
        // ---- prefetch tile t+1 (wraps to 0 at t=63; harmless, unused) ----
        {
            const size_t koff = (size_t)(((t + 1) & 63) * 128) * 1024;
            const size_t voff = (size_t)(((t + 1) & 63) * 128);
            ushort* KsN = Ks[cur ^ 1];
            ushort* VsN = Vs[cur ^ 1];
            gld_lds16(gk0 + koff, KsN + t0 * 512);
            gld_lds16(gk1 + koff, KsN + t1 * 512);
            gld_lds16(gv0 + voff, VsN + t0 * 512);
            gld_lds16(gv1 + voff, VsN + t1 * 512);
        }
        // ---- wait tile t's 4 loads (counted, prefetch stays in flight) ----
        asm volatile("s_waitcnt vmcnt(4)" ::: "memory");
        __builtin_amdgcn_s_barrier();
        __builtin_amdgcn_sched_barrier(0);

        const ushort* KsC = Ks[cur];
        const ushort* VsC = Vs[cur];

        // ---- S^T = K * Q^T  (this wave's 32-v subtile, K=64 over 4 ksteps) ----
        f32x16 st;
#pragma unroll
        for (int r = 0; r < 16; ++r) st[r] = 0.f;
        {
            const int row = (wv * 32 + l31) * 64;
            const int sw = l31 & 7;
            __builtin_amdgcn_s_setprio(1);
#pragma unroll
            for (int ks = 0; ks < 4; ++ks) {
                const int ph = ((ks * 2 + l5) ^ sw) * 8;
                short8 kf = *(const short8*)(KsC + row + ph);
                st = __builtin_amdgcn_mfma_f32_32x32x16_bf16(kf, qf[ks], st, 0, 0, 0);
            }
            __builtin_amdgcn_s_setprio(0);
        }

        // ---- P = exp2(S^T) in regs; rebuild PV A-frag; O += P*V ----
        // st reg r holds P^T value at v = (r&3) + 8*(r>>2) + 4*l5 (p = l31).
        // PV kstep k4 (k8 = wv*2+k4) needs lane(p,l5) octet v = 16k4+8*l5+j.
        // a0..b1 = cvt_pk pairs of e[8k4 + 0..7]; permlane32_swap(a,b)
        // (dst-hi <-> src-lo) yields words: a0'=w0, a1'=w1, b0'=w2, b1'=w3.
#pragma unroll
        for (int k4 = 0; k4 < 2; ++k4) {
            float e[8];
#pragma unroll
            for (int tt = 0; tt < 8; ++tt)
                e[tt] = __builtin_amdgcn_exp2f(st[k4 * 8 + tt]);
            lpart += ((e[0] + e[1]) + (e[2] + e[3])) + ((e[4] + e[5]) + (e[6] + e[7]));
            unsigned int a0, a1, b0, b1;
            asm("v_cvt_pk_bf16_f32 %0, %1, %2" : "=v"(a0) : "v"(e[0]), "v"(e[1]));
            asm("v_cvt_pk_bf16_f32 %0, %1, %2" : "=v"(a1) : "v"(e[2]), "v"(e[3]));
            asm("v_cvt_pk_bf16_f32 %0, %1, %2" : "=v"(b0) : "v"(e[4]), "v"(e[5]));
            asm("v_cvt_pk_bf16_f32 %0, %1, %2" : "=v"(b1) : "v"(e[6]), "v"(e[7]));
            asm("v_permlane32_swap_b32 %0, %1" : "+v"(a0), "+v"(b0));
            asm("v_permlane32_swap_b32 %0, %1" : "+v"(a1), "+v"(b1));
            uint4v pfw = {a0, a1, b0, b1};
            short8 pf = __builtin_bit_cast(short8, pfw);
            const int k8 = wv * 2 + k4;
            __builtin_amdgcn_s_setprio(1);
#pragma unroll
            for (int dt = 0; dt < 2; ++dt) {
                const int d_l = dt * 32 + l31;
                const int ph = ((k8 * 2 + l5) ^ (d_l & 15)) * 8;
                short8 vf = *(const short8*)(VsC + d_l * 128 + ph);
                o[dt] = __builtin_amdgcn_mfma_f32_32x32x16_bf16(pf, vf, o[dt], 0, 0, 0);
            }
            __builtin_amdgcn_s_setprio(0);
        }
        __builtin_amdgcn_sched_barrier(0);
        __builtin_amdgcn_s_barrier();   // all waves done reading buf[cur]
    }

    // ---- cross-wave (4 v-quarters) linear reduce of o and l via LDS ----
    float* RedA = (float*)Ks[0];           // 16 KB used: [wp][32r][64lane]
    float* RedB = (float*)Vs[0];           // 16 KB used
    float* Lq   = (float*)Qs;              // 8 waves x 64 lanes lpart (2 KB)
    Lq[w * 64 + lane] = lpart;             // Qs dead since prologue
    __syncthreads();   // full vmcnt(0)+lgkmcnt(0) drain: wrap-prefetch DMA done
    if (wv >= 2) {
        float* R = (wv == 2) ? RedA : RedB;
#pragma unroll
        for (int dt = 0; dt < 2; ++dt)
#pragma unroll
            for (int r = 0; r < 16; ++r)
                R[wp * 2048 + (dt * 16 + r) * 64 + lane] = o[dt][r];
    }
    __syncthreads();
    if (wv < 2) {
        float* R = (wv == 0) ? RedA : RedB;
#pragma unroll
        for (int dt = 0; dt < 2; ++dt)
#pragma unroll
            for (int r = 0; r < 16; ++r)
                o[dt][r] += R[wp * 2048 + (dt * 16 + r) * 64 + lane];
    }
    __syncthreads();
    if (wv == 1) {
#pragma unroll
        for (int dt = 0; dt < 2; ++dt)
#pragma unroll
            for (int r = 0; r < 16; ++r)
                RedA[wp * 2048 + (dt * 16 + r) * 64 + lane] = o[dt][r];
    }
    __syncthreads();
    if (wv == 0) {
#pragma unroll
        for (int dt = 0; dt < 2; ++dt)
#pragma unroll
            for (int r = 0; r < 16; ++r)
                o[dt][r] += RedA[wp * 2048 + (dt * 16 + r) * 64 + lane];
        float lsum = (Lq[(wp * 4 + 0) * 64 + lane] + Lq[(wp * 4 + 1) * 64 + lane])
                   + (Lq[(wp * 4 + 2) * 64 + lane] + Lq[(wp * 4 + 3) * 64 + lane]);

        // ---- epilogue: normalize by l, write bf16 ----
        float lfull = lsum + __shfl_xor(lsum, 32, 64);
        float rinv = 1.0f / lfull;
#pragma unroll
        for (int r = 0; r < 16; ++r) {
            const int poff = (r & 3) + 8 * (r >> 2) + 4 * l5;
            const float sc = __shfl(rinv, poff, 64);
            const size_t grow = (size_t)(pbase + wp * 32 + poff) * 1024;
#pragma unroll
            for (int dt = 0; dt < 2; ++dt)
                mappedb[grow + h * 64 + dt * 32 + l31] = f2bf(o[dt][r] * sc);
        }
    }
}

// ---------------------------------------------------------------------------
extern "C" void kernel_launch(void* const* d_in, const int* in_sizes, int n_in,
                              void* d_out, int out_size, void* d_ws, size_t ws_size,
                              hipStream_t stream)
{
    const float* query = (const float*)d_in[0];
    const float* key   = (const float*)d_in[1];
    const float* value = (const float*)d_in[2];
    const float* Wq    = (const float*)d_in[3];
    const float* bq    = (const float*)d_in[4];
    const float* Wk    = (const float*)d_in[5];
    const float* bk    = (const float*)d_in[6];
    const float* Wv    = (const float*)d_in[7];
    const float* bv    = (const float*)d_in[8];
    const float* Wo    = (const float*)d_in[9];
    const float* bo    = (const float*)d_in[10];
    float* out = (float*)d_out;

    // ws layout (<= 80 MB): tmpb 64MB | wslot 8MB | queryb 4MB | qb 4MB
    // mappedb aliases tmpb[0:4MB) (tmp dead after vproj).
    // d_out (32MB) used as scratch for kb/vT, fully overwritten by final gemm.
    char* ws = (char*)d_ws;
    ushort* tmpb    = (ushort*)ws;
    ushort* wslot   = (ushort*)(ws + (64ull << 20));
    ushort* queryb  = (ushort*)(ws + (72ull << 20));
    ushort* qb      = (ushort*)(ws + (76ull << 20));
    ushort* mappedb = (ushort*)ws;
    ushort* kb      = (ushort*)d_out;
    ushort* vT      = (ushort*)((char*)d_out + (16ull << 20));

    const float QSCALE = 1.4426950408889634f / 64.0f;   // log2(e)/64 folded into q

    // k-projection: kb[8192,1024] = key @ Wk + bk
    conv_f32_bf16<<<16384, 256, 0, stream>>>(key, tmpb, 8192 * 4096);
    transconv<<<dim3(32, 128), 256, 0, stream>>>(Wk, wslot, 4096, 1024);
    gemm_bt<1, 0><<<dim3(8, 64), 256, 0, stream>>>(tmpb, wslot, bk, kb,
                                                   8192, 1024, 4096, 1.0f);
    // v-projection, TRANSPOSED: vT[1024,8192] = WvT @ value^T  (row bias bv)
    conv_f32_bf16<<<16384, 256, 0, stream>>>(value, tmpb, 8192 * 4096);
    transconv<<<dim3(32, 128), 256, 0, stream>>>(Wv, wslot, 4096, 1024);
    gemm_bt<1, 1><<<dim3(64, 8), 256, 0, stream>>>(wslot, tmpb, bv, vT,
                                                   1024, 8192, 4096, 1.0f);
    // q-projection (pre-scaled): qb[2048,1024] = (query @ Wq + bq) * QSCALE
    conv_f32_bf16<<<1024, 256, 0, stream>>>(query, queryb, 2048 * 1024);
    transconv<<<dim3(32, 32), 256, 0, stream>>>(Wq, wslot, 1024, 1024);
    gemm_bt<1, 0><<<dim3(8, 16), 256, 0, stream>>>(queryb, wslot, bq, qb,
                                                   2048, 1024, 1024, QSCALE);
    // attention -> mappedb [2048,1024] bf16  (8 waves, dbuf K/V, in-reg P)
    attn_mfma<<<512, 512, 0, stream>>>(qb, kb, vT, mappedb);
    // output projection (fp32 out): out[2048,4096] = mapped @ Wo + bo
    transconv<<<dim3(128, 32), 256, 0, stream>>>(Wo, wslot, 1024, 4096);
    gemm_bt<0, 0><<<dim3(32, 16), 256, 0, stream>>>(mappedb, wslot, bo, out,
                                                    2048, 4096, 1024, 1.0f);
}